// Round 5
// baseline (388.111 us; speedup 1.0000x reference)
//
#include <hip/hip_runtime.h>
#include <math.h>

#define B_     256
#define S_     500
#define QD_    128
#define M_     64
#define VD_    256
#define CH_    16
#define NQ_    10000          // q indices in [0, 10000]
#define NQA_   20000          // qa indices in [0, 20000]
#define WROWS  (NQ_ + 1)
#define EAROWS (NQA_ + 1)
#define NC_    128            // columns per scan block
#define MS_    4              // m-split per column

// ---------------------------------------------------------------------------
// Transpose key_mem [64][128] into quad layout kTq[k4*64 + m] = float4 of
// key_mem[m][4k4..4k4+3], so wtab kernel's per-lane reads are coalesced.
// ---------------------------------------------------------------------------
__global__ void kT_kernel(const float* __restrict__ key_mem, float4* __restrict__ kTq)
{
    int i = blockIdx.x * 256 + threadIdx.x;
    if (i < 32 * 64) {
        int m  = i & 63;
        int k4 = i >> 6;
        kTq[i] = *reinterpret_cast<const float4*>(&key_mem[m * QD_ + k4 * 4]);
    }
}

// ---------------------------------------------------------------------------
// wtab[r][m] = softmax_m( q_embed_w[r] . key_mem[m] ),  r in [0, WROWS)
// ---------------------------------------------------------------------------
__global__ __launch_bounds__(256) void wtab_kernel(
    const float*  __restrict__ q_embed_w,
    const float4* __restrict__ kTq,
    float*        __restrict__ wtab)
{
    __shared__ float4 q4[16][32];

    const int tid = threadIdx.x;
    const int r0  = blockIdx.x * 16;

    for (int i = tid; i < 512; i += 256) {
        int row = i >> 5, k4 = i & 31;
        int r   = r0 + row; if (r > NQ_) r = NQ_;
        q4[row][k4] = *reinterpret_cast<const float4*>(
            &q_embed_w[(size_t)r * QD_ + k4 * 4]);
    }
    __syncthreads();

    const int wave = tid >> 6, lane = tid & 63;
    const int rr = wave * 4;

    float s0 = 0.f, s1 = 0.f, s2 = 0.f, s3 = 0.f;
    for (int k4 = 0; k4 < 32; ++k4) {
        float4 kv = kTq[k4 * 64 + lane];
        float4 a0 = q4[rr + 0][k4];
        float4 a1 = q4[rr + 1][k4];
        float4 a2 = q4[rr + 2][k4];
        float4 a3 = q4[rr + 3][k4];
        s0 = fmaf(a0.x, kv.x, s0); s0 = fmaf(a0.y, kv.y, s0);
        s0 = fmaf(a0.z, kv.z, s0); s0 = fmaf(a0.w, kv.w, s0);
        s1 = fmaf(a1.x, kv.x, s1); s1 = fmaf(a1.y, kv.y, s1);
        s1 = fmaf(a1.z, kv.z, s1); s1 = fmaf(a1.w, kv.w, s1);
        s2 = fmaf(a2.x, kv.x, s2); s2 = fmaf(a2.y, kv.y, s2);
        s2 = fmaf(a2.z, kv.z, s2); s2 = fmaf(a2.w, kv.w, s2);
        s3 = fmaf(a3.x, kv.x, s3); s3 = fmaf(a3.y, kv.y, s3);
        s3 = fmaf(a3.z, kv.z, s3); s3 = fmaf(a3.w, kv.w, s3);
    }

    float s[4] = { s0, s1, s2, s3 };
    #pragma unroll
    for (int j = 0; j < 4; ++j) {
        float mx = s[j];
        #pragma unroll
        for (int off = 32; off; off >>= 1) mx = fmaxf(mx, __shfl_xor(mx, off));
        float e = __expf(s[j] - mx);
        float sum = e;
        #pragma unroll
        for (int off = 32; off; off >>= 1) sum += __shfl_xor(sum, off);
        if (r0 + rr + j < WROWS)
            wtab[(size_t)(r0 + rr + j) * 64 + lane] = e / sum;
    }
}

// ---------------------------------------------------------------------------
// eatab[r][0..255]   = sigmoid(qa_embed_w[r] @ erase_W + erase_b)
// eatab[r][256..511] = tanh   (qa_embed_w[r] @ add_W   + add_b)
// ---------------------------------------------------------------------------
__global__ __launch_bounds__(512) void eatab_kernel(
    const float* __restrict__ qa_embed_w,
    const float* __restrict__ erase_W,
    const float* __restrict__ erase_b,
    const float* __restrict__ add_W,
    const float* __restrict__ add_b,
    float*       __restrict__ eatab)
{
    __shared__ float4 qa4[16][32];

    const int tid = threadIdx.x;
    const int r0  = blockIdx.x * 16;

    {
        int row = tid >> 5, k4 = tid & 31;
        int r   = r0 + row; if (r > NQA_) r = NQA_;
        qa4[row][k4] = *reinterpret_cast<const float4*>(
            &qa_embed_w[(size_t)r * QD_ + k4 * 4]);
    }
    __syncthreads();

    const int  c   = tid & 255;
    const bool isE = tid < 256;
    const float* Wp = isE ? erase_W : add_W;

    float acc[16];
    #pragma unroll
    for (int r = 0; r < 16; ++r) acc[r] = 0.f;

    for (int k4 = 0; k4 < 32; ++k4) {
        float w0 = Wp[(size_t)(k4 * 4 + 0) * 256 + c];
        float w1 = Wp[(size_t)(k4 * 4 + 1) * 256 + c];
        float w2 = Wp[(size_t)(k4 * 4 + 2) * 256 + c];
        float w3 = Wp[(size_t)(k4 * 4 + 3) * 256 + c];
        #pragma unroll
        for (int r = 0; r < 16; ++r) {
            float4 qv = qa4[r][k4];
            acc[r] = fmaf(qv.x, w0, acc[r]);
            acc[r] = fmaf(qv.y, w1, acc[r]);
            acc[r] = fmaf(qv.z, w2, acc[r]);
            acc[r] = fmaf(qv.w, w3, acc[r]);
        }
    }

    const float bias = isE ? erase_b[c] : add_b[c];
    #pragma unroll
    for (int r = 0; r < 16; ++r) {
        float x = acc[r] + bias;
        float y;
        if (isE) {
            y = 1.f / (1.f + __expf(-x));
        } else {
            float t  = __expf(-2.f * fabsf(x));
            float ta = (1.f - t) / (1.f + t);
            y = (x < 0.f) ? -ta : ta;
        }
        if (r0 + r < EAROWS)
            eatab[(size_t)(r0 + r) * 512 + tid] = y;
    }
}

// ---------------------------------------------------------------------------
// Scan: grid = B_*2 (2 blocks per batch, each owns NC_=128 columns),
// 512 threads = 8 waves; 2 blocks/CU -> 16 waves/CU (4/SIMD).
// Thread tid: col = tid>>2 (within block's column range), ms = tid&3 owns
// m-quarter [ms*16, ms*16+16) -> mv[4] float4 state in VGPRs.
// Per step: 4 broadcast ds_read_b128 (w), 48 FMAs, 2 lane-local shfl_xor.
// w double-buffered in LDS; e/a prefetched global->VGPR per chunk (T14).
// ---------------------------------------------------------------------------
__global__ __launch_bounds__(512, 1) void scan_kernel(
    const int*   __restrict__ q_data,
    const int*   __restrict__ qa_data,
    const float* __restrict__ init_mv,
    const float* __restrict__ wtab,
    const float* __restrict__ eatab,
    float*       __restrict__ out)
{
    __shared__ float w_lds[2][CH_ * 64];
    __shared__ int   qrow[S_];
    __shared__ int   qarow[S_];

    const int b   = blockIdx.x >> 1;
    const int cb  = blockIdx.x & 1;
    const int tid = threadIdx.x;
    const int col = cb * NC_ + (tid >> 2);
    const int ms  = tid & 3;
    const int mo  = ms * 16;

    for (int i = tid; i < S_; i += 512) {
        qrow[i]  = q_data[b * S_ + i];
        qarow[i] = qa_data[b * S_ + i];
    }
    __syncthreads();

    // Mv state: m = mo + q*4 + k, column col
    float4 mv[4];
    #pragma unroll
    for (int q = 0; q < 4; ++q) {
        mv[q].x = init_mv[(mo + q * 4 + 0) * VD_ + col];
        mv[q].y = init_mv[(mo + q * 4 + 1) * VD_ + col];
        mv[q].z = init_mv[(mo + q * 4 + 2) * VD_ + col];
        mv[q].w = init_mv[(mo + q * 4 + 3) * VD_ + col];
    }
    if (ms == 0) out[(size_t)b * S_ * VD_ + col] = 0.f;

    // chunk 0 staging: w -> LDS, e/a -> registers
    if (tid < 256) {
        int wstep = tid >> 4, wq4 = tid & 15;
        *reinterpret_cast<float4*>(&w_lds[0][wstep * 64 + wq4 * 4]) =
            *reinterpret_cast<const float4*>(&wtab[(size_t)qrow[wstep] * 64 + wq4 * 4]);
    }
    float ec[CH_], ac[CH_];
    #pragma unroll
    for (int j = 0; j < CH_; ++j) {
        const float* rowp = &eatab[(size_t)qarow[j] * 512 + col];
        ec[j] = rowp[0];
        ac[j] = rowp[256];
    }
    __syncthreads();

    const int nch = (S_ + CH_ - 1) / CH_;
    for (int c = 0; c < nch; ++c) {
        const int  tb   = c * CH_;
        const int  tcnt = (S_ - tb < CH_) ? (S_ - tb) : CH_;
        const int  buf  = c & 1;
        const bool hn   = (c + 1 < nch);

        // issue next chunk's loads early (T14)
        float4 rw;
        float  en[CH_], an[CH_];
        if (hn) {
            if (tid < 256) {
                int wstep = tid >> 4, wq4 = tid & 15;
                int st = tb + CH_ + wstep; if (st >= S_) st = S_ - 1;
                rw = *reinterpret_cast<const float4*>(
                    &wtab[(size_t)qrow[st] * 64 + wq4 * 4]);
            }
            #pragma unroll
            for (int j = 0; j < CH_; ++j) {
                int st = tb + CH_ + j; if (st >= S_) st = S_ - 1;
                const float* rowp = &eatab[(size_t)qarow[st] * 512 + col];
                en[j] = rowp[0];
                an[j] = rowp[256];
            }
        }

        float* outp = &out[((size_t)b * S_ + tb + 1) * VD_ + col];

        if (tcnt == CH_) {
            #pragma unroll
            for (int tt = 0; tt < CH_; ++tt) {
                const int  t  = tb + tt;
                const bool wr = qrow[t] >= 1;
                const float em = wr ? ec[tt] : 0.f;
                const float am = wr ? ac[tt] : 0.f;
                const float* wrow = &w_lds[buf][tt * 64 + mo];

                float rd0 = 0.f, rd1 = 0.f, rd2 = 0.f, rd3 = 0.f;
                #pragma unroll
                for (int q = 0; q < 4; ++q) {
                    float4 wq = *reinterpret_cast<const float4*>(wrow + q * 4);
                    float4 v  = mv[q];
                    rd0 = fmaf(wq.x, v.x, rd0);
                    rd1 = fmaf(wq.y, v.y, rd1);
                    rd2 = fmaf(wq.z, v.z, rd2);
                    rd3 = fmaf(wq.w, v.w, rd3);
                    mv[q].x = fmaf(wq.x, fmaf(-em, v.x, am), v.x);
                    mv[q].y = fmaf(wq.y, fmaf(-em, v.y, am), v.y);
                    mv[q].z = fmaf(wq.z, fmaf(-em, v.z, am), v.z);
                    mv[q].w = fmaf(wq.w, fmaf(-em, v.w, am), v.w);
                }
                float rd = (rd0 + rd1) + (rd2 + rd3);
                rd += __shfl_xor(rd, 1);
                rd += __shfl_xor(rd, 2);
                // full chunks always have t+1 < S_ (last full chunk ends at 496)
                if (ms == 0) outp[(size_t)tt * VD_] = rd;
            }
        } else {
            for (int tt = 0; tt < tcnt; ++tt) {
                const int  t  = tb + tt;
                const bool wr = qrow[t] >= 1;
                const float em = wr ? ec[tt] : 0.f;
                const float am = wr ? ac[tt] : 0.f;
                const float* wrow = &w_lds[buf][tt * 64 + mo];

                float rd0 = 0.f, rd1 = 0.f, rd2 = 0.f, rd3 = 0.f;
                #pragma unroll
                for (int q = 0; q < 4; ++q) {
                    float4 wq = *reinterpret_cast<const float4*>(wrow + q * 4);
                    float4 v  = mv[q];
                    rd0 = fmaf(wq.x, v.x, rd0);
                    rd1 = fmaf(wq.y, v.y, rd1);
                    rd2 = fmaf(wq.z, v.z, rd2);
                    rd3 = fmaf(wq.w, v.w, rd3);
                    mv[q].x = fmaf(wq.x, fmaf(-em, v.x, am), v.x);
                    mv[q].y = fmaf(wq.y, fmaf(-em, v.y, am), v.y);
                    mv[q].z = fmaf(wq.z, fmaf(-em, v.z, am), v.z);
                    mv[q].w = fmaf(wq.w, fmaf(-em, v.w, am), v.w);
                }
                float rd = (rd0 + rd1) + (rd2 + rd3);
                rd += __shfl_xor(rd, 1);
                rd += __shfl_xor(rd, 2);
                if (ms == 0 && t + 1 < S_) outp[(size_t)tt * VD_] = rd;
            }
        }

        // commit staged data (write-late)
        if (hn) {
            if (tid < 256) {
                int wstep = tid >> 4, wq4 = tid & 15;
                *reinterpret_cast<float4*>(&w_lds[buf ^ 1][wstep * 64 + wq4 * 4]) = rw;
            }
            #pragma unroll
            for (int j = 0; j < CH_; ++j) { ec[j] = en[j]; ac[j] = an[j]; }
        }
        __syncthreads();
    }
}

// ---------------------------------------------------------------------------
extern "C" void kernel_launch(void* const* d_in, const int* in_sizes, int n_in,
                              void* d_out, int out_size, void* d_ws, size_t ws_size,
                              hipStream_t stream)
{
    const int*   q_data  = (const int*)  d_in[0];
    const int*   qa_data = (const int*)  d_in[1];
    const float* q_emb   = (const float*)d_in[2];
    const float* qa_emb  = (const float*)d_in[3];
    const float* key_mem = (const float*)d_in[4];
    const float* init_mv = (const float*)d_in[5];
    const float* erase_W = (const float*)d_in[6];
    const float* erase_b = (const float*)d_in[7];
    const float* add_W   = (const float*)d_in[8];
    const float* add_b   = (const float*)d_in[9];
    float* out = (float*)d_out;

    char* ws = (char*)d_ws;
    float4* kTq = (float4*)ws;
    size_t off = (size_t)2048 * sizeof(float4);               // 32 KB
    float* wtab = (float*)(ws + off);
    off += (size_t)WROWS * 64 * sizeof(float);                // 2.56 MB
    off = (off + 255) & ~(size_t)255;
    float* eatab = (float*)(ws + off);
    off += (size_t)EAROWS * 512 * sizeof(float);              // 40.96 MB

    kT_kernel<<<dim3(8), dim3(256), 0, stream>>>(key_mem, kTq);
    wtab_kernel<<<dim3((WROWS + 15) / 16), dim3(256), 0, stream>>>(
        q_emb, kTq, wtab);
    eatab_kernel<<<dim3((EAROWS + 15) / 16), dim3(512), 0, stream>>>(
        qa_emb, erase_W, erase_b, add_W, add_b, eatab);
    scan_kernel<<<dim3(B_ * 2), dim3(512), 0, stream>>>(
        q_data, qa_data, init_mv, wtab, eatab, out);
}

// Round 6
// 369.761 us; speedup vs baseline: 1.0496x; 1.0496x over previous
//
#include <hip/hip_runtime.h>
#include <math.h>

#define B_     256
#define S_     500
#define QD_    128
#define M_     64
#define VD_    256
#define CH_    16
#define NQ_    10000          // q indices in [0, 10000]
#define NQA_   20000          // qa indices in [0, 20000]
#define WROWS  (NQ_ + 1)
#define EAROWS (NQA_ + 1)

// ---------------------------------------------------------------------------
// Transpose key_mem [64][128] into quad layout kTq[k4*64 + m] = float4 of
// key_mem[m][4k4..4k4+3], so wtab kernel's per-lane reads are coalesced.
// ---------------------------------------------------------------------------
__global__ void kT_kernel(const float* __restrict__ key_mem, float4* __restrict__ kTq)
{
    int i = blockIdx.x * 256 + threadIdx.x;
    if (i < 32 * 64) {
        int m  = i & 63;
        int k4 = i >> 6;
        kTq[i] = *reinterpret_cast<const float4*>(&key_mem[m * QD_ + k4 * 4]);
    }
}

// ---------------------------------------------------------------------------
// wtab[r][m] = softmax_m( q_embed_w[r] . key_mem[m] ),  r in [0, WROWS)
// ---------------------------------------------------------------------------
__global__ __launch_bounds__(256) void wtab_kernel(
    const float*  __restrict__ q_embed_w,
    const float4* __restrict__ kTq,
    float*        __restrict__ wtab)
{
    __shared__ float4 q4[16][32];

    const int tid = threadIdx.x;
    const int r0  = blockIdx.x * 16;

    for (int i = tid; i < 512; i += 256) {
        int row = i >> 5, k4 = i & 31;
        int r   = r0 + row; if (r > NQ_) r = NQ_;
        q4[row][k4] = *reinterpret_cast<const float4*>(
            &q_embed_w[(size_t)r * QD_ + k4 * 4]);
    }
    __syncthreads();

    const int wave = tid >> 6, lane = tid & 63;
    const int rr = wave * 4;

    float s0 = 0.f, s1 = 0.f, s2 = 0.f, s3 = 0.f;
    for (int k4 = 0; k4 < 32; ++k4) {
        float4 kv = kTq[k4 * 64 + lane];
        float4 a0 = q4[rr + 0][k4];
        float4 a1 = q4[rr + 1][k4];
        float4 a2 = q4[rr + 2][k4];
        float4 a3 = q4[rr + 3][k4];
        s0 = fmaf(a0.x, kv.x, s0); s0 = fmaf(a0.y, kv.y, s0);
        s0 = fmaf(a0.z, kv.z, s0); s0 = fmaf(a0.w, kv.w, s0);
        s1 = fmaf(a1.x, kv.x, s1); s1 = fmaf(a1.y, kv.y, s1);
        s1 = fmaf(a1.z, kv.z, s1); s1 = fmaf(a1.w, kv.w, s1);
        s2 = fmaf(a2.x, kv.x, s2); s2 = fmaf(a2.y, kv.y, s2);
        s2 = fmaf(a2.z, kv.z, s2); s2 = fmaf(a2.w, kv.w, s2);
        s3 = fmaf(a3.x, kv.x, s3); s3 = fmaf(a3.y, kv.y, s3);
        s3 = fmaf(a3.z, kv.z, s3); s3 = fmaf(a3.w, kv.w, s3);
    }

    float s[4] = { s0, s1, s2, s3 };
    #pragma unroll
    for (int j = 0; j < 4; ++j) {
        float mx = s[j];
        #pragma unroll
        for (int off = 32; off; off >>= 1) mx = fmaxf(mx, __shfl_xor(mx, off));
        float e = __expf(s[j] - mx);
        float sum = e;
        #pragma unroll
        for (int off = 32; off; off >>= 1) sum += __shfl_xor(sum, off);
        if (r0 + rr + j < WROWS)
            wtab[(size_t)(r0 + rr + j) * 64 + lane] = e / sum;
    }
}

// ---------------------------------------------------------------------------
// eatab[r][0..255]   = sigmoid(qa_embed_w[r] @ erase_W + erase_b)
// eatab[r][256..511] = tanh   (qa_embed_w[r] @ add_W   + add_b)
// ---------------------------------------------------------------------------
__global__ __launch_bounds__(512) void eatab_kernel(
    const float* __restrict__ qa_embed_w,
    const float* __restrict__ erase_W,
    const float* __restrict__ erase_b,
    const float* __restrict__ add_W,
    const float* __restrict__ add_b,
    float*       __restrict__ eatab)
{
    __shared__ float4 qa4[16][32];

    const int tid = threadIdx.x;
    const int r0  = blockIdx.x * 16;

    {
        int row = tid >> 5, k4 = tid & 31;
        int r   = r0 + row; if (r > NQA_) r = NQA_;
        qa4[row][k4] = *reinterpret_cast<const float4*>(
            &qa_embed_w[(size_t)r * QD_ + k4 * 4]);
    }
    __syncthreads();

    const int  c   = tid & 255;
    const bool isE = tid < 256;
    const float* Wp = isE ? erase_W : add_W;

    float acc[16];
    #pragma unroll
    for (int r = 0; r < 16; ++r) acc[r] = 0.f;

    for (int k4 = 0; k4 < 32; ++k4) {
        float w0 = Wp[(size_t)(k4 * 4 + 0) * 256 + c];
        float w1 = Wp[(size_t)(k4 * 4 + 1) * 256 + c];
        float w2 = Wp[(size_t)(k4 * 4 + 2) * 256 + c];
        float w3 = Wp[(size_t)(k4 * 4 + 3) * 256 + c];
        #pragma unroll
        for (int r = 0; r < 16; ++r) {
            float4 qv = qa4[r][k4];
            acc[r] = fmaf(qv.x, w0, acc[r]);
            acc[r] = fmaf(qv.y, w1, acc[r]);
            acc[r] = fmaf(qv.z, w2, acc[r]);
            acc[r] = fmaf(qv.w, w3, acc[r]);
        }
    }

    const float bias = isE ? erase_b[c] : add_b[c];
    #pragma unroll
    for (int r = 0; r < 16; ++r) {
        float x = acc[r] + bias;
        float y;
        if (isE) {
            y = 1.f / (1.f + __expf(-x));
        } else {
            float t  = __expf(-2.f * fabsf(x));
            float ta = (1.f - t) / (1.f + t);
            y = (x < 0.f) ? -ta : ta;
        }
        if (r0 + r < EAROWS)
            eatab[(size_t)(r0 + r) * 512 + tid] = y;
    }
}

// ---------------------------------------------------------------------------
// Scan: 256 blocks (1/batch) x 512 threads (8 waves/CU).
// Thread tid owns COLUMN PAIR col = (tid>>2)*2 (+0,+1) and m-quarter
// mo = (tid&3)*16: mv0[4]/mv1[4] float4 state (32 VGPRs).
// One ds_read_b128 of w feeds BOTH columns -> LDS w-traffic halves vs
// 1-col/thread (per-CU LDS pipe was the binding constraint).
// Per step: 4 ds_read_b128, 96 FMA, 2x2 quad-local shfl_xor, float2 store.
// e/a prefetched global->VGPR per chunk as float2 (T14 split); all chunk
// arrays statically indexed (tail chunk = unrolled + guard, rule #20).
// ---------------------------------------------------------------------------
__global__ __launch_bounds__(512, 1) void scan_kernel(
    const int*   __restrict__ q_data,
    const int*   __restrict__ qa_data,
    const float* __restrict__ init_mv,
    const float* __restrict__ wtab,
    const float* __restrict__ eatab,
    float*       __restrict__ out)
{
    __shared__ float w_lds[2][CH_ * 64];
    __shared__ int   qrow[S_];
    __shared__ int   qarow[S_];

    const int b   = blockIdx.x;
    const int tid = threadIdx.x;
    const int col = (tid >> 2) * 2;     // columns col, col+1
    const int ms  = tid & 3;
    const int mo  = ms * 16;

    for (int i = tid; i < S_; i += 512) {
        qrow[i]  = q_data[b * S_ + i];
        qarow[i] = qa_data[b * S_ + i];
    }
    __syncthreads();

    // Mv state: m = mo + q*4 + k; column col in mv0, col+1 in mv1
    float4 mv0[4], mv1[4];
    #pragma unroll
    for (int q = 0; q < 4; ++q) {
        float2 i0 = *reinterpret_cast<const float2*>(&init_mv[(mo + q * 4 + 0) * VD_ + col]);
        float2 i1 = *reinterpret_cast<const float2*>(&init_mv[(mo + q * 4 + 1) * VD_ + col]);
        float2 i2 = *reinterpret_cast<const float2*>(&init_mv[(mo + q * 4 + 2) * VD_ + col]);
        float2 i3 = *reinterpret_cast<const float2*>(&init_mv[(mo + q * 4 + 3) * VD_ + col]);
        mv0[q].x = i0.x; mv1[q].x = i0.y;
        mv0[q].y = i1.x; mv1[q].y = i1.y;
        mv0[q].z = i2.x; mv1[q].z = i2.y;
        mv0[q].w = i3.x; mv1[q].w = i3.y;
    }
    if (ms == 0)
        *reinterpret_cast<float2*>(&out[(size_t)b * S_ * VD_ + col]) = make_float2(0.f, 0.f);

    // chunk 0 staging: w -> LDS, e/a -> registers (float2 per column pair)
    if (tid < 256) {
        int wstep = tid >> 4, wq4 = tid & 15;
        *reinterpret_cast<float4*>(&w_lds[0][wstep * 64 + wq4 * 4]) =
            *reinterpret_cast<const float4*>(&wtab[(size_t)qrow[wstep] * 64 + wq4 * 4]);
    }
    float2 ec[CH_], ac[CH_];
    #pragma unroll
    for (int j = 0; j < CH_; ++j) {
        const float* rowp = &eatab[(size_t)qarow[j] * 512 + col];
        ec[j] = *reinterpret_cast<const float2*>(&rowp[0]);
        ac[j] = *reinterpret_cast<const float2*>(&rowp[256]);
    }
    __syncthreads();

    const int nch = (S_ + CH_ - 1) / CH_;
    for (int c = 0; c < nch; ++c) {
        const int  tb   = c * CH_;
        const int  full = (S_ - tb >= CH_);
        const int  buf  = c & 1;
        const bool hn   = (c + 1 < nch);

        // issue next chunk's loads early (T14)
        float4 rw;
        float2 en[CH_], an[CH_];
        if (hn) {
            if (tid < 256) {
                int wstep = tid >> 4, wq4 = tid & 15;
                int st = tb + CH_ + wstep; if (st >= S_) st = S_ - 1;
                rw = *reinterpret_cast<const float4*>(
                    &wtab[(size_t)qrow[st] * 64 + wq4 * 4]);
            }
            #pragma unroll
            for (int j = 0; j < CH_; ++j) {
                int st = tb + CH_ + j; if (st >= S_) st = S_ - 1;
                const float* rowp = &eatab[(size_t)qarow[st] * 512 + col];
                en[j] = *reinterpret_cast<const float2*>(&rowp[0]);
                an[j] = *reinterpret_cast<const float2*>(&rowp[256]);
            }
        }

        float* outp = &out[((size_t)b * S_ + tb + 1) * VD_ + col];

        #define STEP_BODY(tt)                                                       \
        {                                                                           \
            const int  t  = tb + (tt);                                              \
            const bool wr = qrow[t] >= 1;                                           \
            const float em0 = wr ? ec[(tt)].x : 0.f;                                \
            const float am0 = wr ? ac[(tt)].x : 0.f;                                \
            const float em1 = wr ? ec[(tt)].y : 0.f;                                \
            const float am1 = wr ? ac[(tt)].y : 0.f;                                \
            const float* wrow = &w_lds[buf][(tt) * 64 + mo];                        \
            float r0a = 0.f, r0b = 0.f, r1a = 0.f, r1b = 0.f;                       \
            _Pragma("unroll")                                                       \
            for (int q = 0; q < 4; ++q) {                                           \
                float4 wq = *reinterpret_cast<const float4*>(wrow + q * 4);         \
                float4 v0 = mv0[q];                                                 \
                float4 v1 = mv1[q];                                                 \
                r0a = fmaf(wq.x, v0.x, r0a); r0b = fmaf(wq.y, v0.y, r0b);           \
                r0a = fmaf(wq.z, v0.z, r0a); r0b = fmaf(wq.w, v0.w, r0b);           \
                r1a = fmaf(wq.x, v1.x, r1a); r1b = fmaf(wq.y, v1.y, r1b);           \
                r1a = fmaf(wq.z, v1.z, r1a); r1b = fmaf(wq.w, v1.w, r1b);           \
                mv0[q].x = fmaf(wq.x, fmaf(-em0, v0.x, am0), v0.x);                 \
                mv0[q].y = fmaf(wq.y, fmaf(-em0, v0.y, am0), v0.y);                 \
                mv0[q].z = fmaf(wq.z, fmaf(-em0, v0.z, am0), v0.z);                 \
                mv0[q].w = fmaf(wq.w, fmaf(-em0, v0.w, am0), v0.w);                 \
                mv1[q].x = fmaf(wq.x, fmaf(-em1, v1.x, am1), v1.x);                 \
                mv1[q].y = fmaf(wq.y, fmaf(-em1, v1.y, am1), v1.y);                 \
                mv1[q].z = fmaf(wq.z, fmaf(-em1, v1.z, am1), v1.z);                 \
                mv1[q].w = fmaf(wq.w, fmaf(-em1, v1.w, am1), v1.w);                 \
            }                                                                       \
            float rd0 = r0a + r0b;                                                  \
            rd0 += __shfl_xor(rd0, 1);                                              \
            rd0 += __shfl_xor(rd0, 2);                                              \
            float rd1 = r1a + r1b;                                                  \
            rd1 += __shfl_xor(rd1, 1);                                              \
            rd1 += __shfl_xor(rd1, 2);                                              \
            if (ms == 0 && (t + 1 < S_))                                            \
                *reinterpret_cast<float2*>(&outp[(size_t)(tt) * VD_]) =             \
                    make_float2(rd0, rd1);                                          \
        }

        if (full) {
            #pragma unroll
            for (int tt = 0; tt < CH_; ++tt) STEP_BODY(tt)
        } else {
            #pragma unroll
            for (int tt = 0; tt < CH_; ++tt) {
                if (tb + tt < S_) STEP_BODY(tt)
            }
        }
        #undef STEP_BODY

        // commit staged data (write-late)
        if (hn) {
            if (tid < 256) {
                int wstep = tid >> 4, wq4 = tid & 15;
                *reinterpret_cast<float4*>(&w_lds[buf ^ 1][wstep * 64 + wq4 * 4]) = rw;
            }
            #pragma unroll
            for (int j = 0; j < CH_; ++j) { ec[j] = en[j]; ac[j] = an[j]; }
        }
        __syncthreads();
    }
}

// ---------------------------------------------------------------------------
extern "C" void kernel_launch(void* const* d_in, const int* in_sizes, int n_in,
                              void* d_out, int out_size, void* d_ws, size_t ws_size,
                              hipStream_t stream)
{
    const int*   q_data  = (const int*)  d_in[0];
    const int*   qa_data = (const int*)  d_in[1];
    const float* q_emb   = (const float*)d_in[2];
    const float* qa_emb  = (const float*)d_in[3];
    const float* key_mem = (const float*)d_in[4];
    const float* init_mv = (const float*)d_in[5];
    const float* erase_W = (const float*)d_in[6];
    const float* erase_b = (const float*)d_in[7];
    const float* add_W   = (const float*)d_in[8];
    const float* add_b   = (const float*)d_in[9];
    float* out = (float*)d_out;

    char* ws = (char*)d_ws;
    float4* kTq = (float4*)ws;
    size_t off = (size_t)2048 * sizeof(float4);               // 32 KB
    float* wtab = (float*)(ws + off);
    off += (size_t)WROWS * 64 * sizeof(float);                // 2.56 MB
    off = (off + 255) & ~(size_t)255;
    float* eatab = (float*)(ws + off);
    off += (size_t)EAROWS * 512 * sizeof(float);              // 40.96 MB

    kT_kernel<<<dim3(8), dim3(256), 0, stream>>>(key_mem, kTq);
    wtab_kernel<<<dim3((WROWS + 15) / 16), dim3(256), 0, stream>>>(
        q_emb, kTq, wtab);
    eatab_kernel<<<dim3((EAROWS + 15) / 16), dim3(512), 0, stream>>>(
        qa_emb, erase_W, erase_b, add_W, add_b, eatab);
    scan_kernel<<<dim3(B_), dim3(512), 0, stream>>>(
        q_data, qa_data, init_mv, wtab, eatab, out);
}

// Round 7
// 332.940 us; speedup vs baseline: 1.1657x; 1.1106x over previous
//
#include <hip/hip_runtime.h>
#include <math.h>

#define B_     256
#define S_     500
#define QD_    128
#define M_     64
#define VD_    256
#define CH_    16
#define NQ_    10000          // q indices in [0, 10000]
#define NQA_   20000          // qa indices in [0, 20000]
#define WROWS  (NQ_ + 1)
#define EAROWS (NQA_ + 1)

typedef unsigned int u32;

// global -> LDS async copy, 16B per lane. LDS dest must be wave-uniform
// base + lane*16 (we pass (idx & ~63)-based base, lanes fill linearly).
__device__ __forceinline__ void gload_lds16(const float* g, float* l)
{
    __builtin_amdgcn_global_load_lds(
        (const __attribute__((address_space(1))) u32*)(const void*)g,
        (__attribute__((address_space(3))) u32*)(void*)l, 16, 0, 0);
}

// ---------------------------------------------------------------------------
// Transpose key_mem [64][128] into quad layout kTq[k4*64 + m].
// ---------------------------------------------------------------------------
__global__ void kT_kernel(const float* __restrict__ key_mem, float4* __restrict__ kTq)
{
    int i = blockIdx.x * 256 + threadIdx.x;
    if (i < 32 * 64) {
        int m  = i & 63;
        int k4 = i >> 6;
        kTq[i] = *reinterpret_cast<const float4*>(&key_mem[m * QD_ + k4 * 4]);
    }
}

// ---------------------------------------------------------------------------
// wtab[r][m] = softmax_m( q_embed_w[r] . key_mem[m] ),  r in [0, WROWS)
// ---------------------------------------------------------------------------
__global__ __launch_bounds__(256) void wtab_kernel(
    const float*  __restrict__ q_embed_w,
    const float4* __restrict__ kTq,
    float*        __restrict__ wtab)
{
    __shared__ float4 q4[16][32];

    const int tid = threadIdx.x;
    const int r0  = blockIdx.x * 16;

    for (int i = tid; i < 512; i += 256) {
        int row = i >> 5, k4 = i & 31;
        int r   = r0 + row; if (r > NQ_) r = NQ_;
        q4[row][k4] = *reinterpret_cast<const float4*>(
            &q_embed_w[(size_t)r * QD_ + k4 * 4]);
    }
    __syncthreads();

    const int wave = tid >> 6, lane = tid & 63;
    const int rr = wave * 4;

    float s0 = 0.f, s1 = 0.f, s2 = 0.f, s3 = 0.f;
    for (int k4 = 0; k4 < 32; ++k4) {
        float4 kv = kTq[k4 * 64 + lane];
        float4 a0 = q4[rr + 0][k4];
        float4 a1 = q4[rr + 1][k4];
        float4 a2 = q4[rr + 2][k4];
        float4 a3 = q4[rr + 3][k4];
        s0 = fmaf(a0.x, kv.x, s0); s0 = fmaf(a0.y, kv.y, s0);
        s0 = fmaf(a0.z, kv.z, s0); s0 = fmaf(a0.w, kv.w, s0);
        s1 = fmaf(a1.x, kv.x, s1); s1 = fmaf(a1.y, kv.y, s1);
        s1 = fmaf(a1.z, kv.z, s1); s1 = fmaf(a1.w, kv.w, s1);
        s2 = fmaf(a2.x, kv.x, s2); s2 = fmaf(a2.y, kv.y, s2);
        s2 = fmaf(a2.z, kv.z, s2); s2 = fmaf(a2.w, kv.w, s2);
        s3 = fmaf(a3.x, kv.x, s3); s3 = fmaf(a3.y, kv.y, s3);
        s3 = fmaf(a3.z, kv.z, s3); s3 = fmaf(a3.w, kv.w, s3);
    }

    float s[4] = { s0, s1, s2, s3 };
    #pragma unroll
    for (int j = 0; j < 4; ++j) {
        float mx = s[j];
        #pragma unroll
        for (int off = 32; off; off >>= 1) mx = fmaxf(mx, __shfl_xor(mx, off));
        float e = __expf(s[j] - mx);
        float sum = e;
        #pragma unroll
        for (int off = 32; off; off >>= 1) sum += __shfl_xor(sum, off);
        if (r0 + rr + j < WROWS)
            wtab[(size_t)(r0 + rr + j) * 64 + lane] = e / sum;
    }
}

// ---------------------------------------------------------------------------
// eatab[r][0..255]   = sigmoid(qa_embed_w[r] @ erase_W + erase_b)
// eatab[r][256..511] = tanh   (qa_embed_w[r] @ add_W   + add_b)
// ---------------------------------------------------------------------------
__global__ __launch_bounds__(512) void eatab_kernel(
    const float* __restrict__ qa_embed_w,
    const float* __restrict__ erase_W,
    const float* __restrict__ erase_b,
    const float* __restrict__ add_W,
    const float* __restrict__ add_b,
    float*       __restrict__ eatab)
{
    __shared__ float4 qa4[16][32];

    const int tid = threadIdx.x;
    const int r0  = blockIdx.x * 16;

    {
        int row = tid >> 5, k4 = tid & 31;
        int r   = r0 + row; if (r > NQA_) r = NQA_;
        qa4[row][k4] = *reinterpret_cast<const float4*>(
            &qa_embed_w[(size_t)r * QD_ + k4 * 4]);
    }
    __syncthreads();

    const int  c   = tid & 255;
    const bool isE = tid < 256;
    const float* Wp = isE ? erase_W : add_W;

    float acc[16];
    #pragma unroll
    for (int r = 0; r < 16; ++r) acc[r] = 0.f;

    for (int k4 = 0; k4 < 32; ++k4) {
        float w0 = Wp[(size_t)(k4 * 4 + 0) * 256 + c];
        float w1 = Wp[(size_t)(k4 * 4 + 1) * 256 + c];
        float w2 = Wp[(size_t)(k4 * 4 + 2) * 256 + c];
        float w3 = Wp[(size_t)(k4 * 4 + 3) * 256 + c];
        #pragma unroll
        for (int r = 0; r < 16; ++r) {
            float4 qv = qa4[r][k4];
            acc[r] = fmaf(qv.x, w0, acc[r]);
            acc[r] = fmaf(qv.y, w1, acc[r]);
            acc[r] = fmaf(qv.z, w2, acc[r]);
            acc[r] = fmaf(qv.w, w3, acc[r]);
        }
    }

    const float bias = isE ? erase_b[c] : add_b[c];
    #pragma unroll
    for (int r = 0; r < 16; ++r) {
        float x = acc[r] + bias;
        float y;
        if (isE) {
            y = 1.f / (1.f + __expf(-x));
        } else {
            float t  = __expf(-2.f * fabsf(x));
            float ta = (1.f - t) / (1.f + t);
            y = (x < 0.f) ? -ta : ta;
        }
        if (r0 + r < EAROWS)
            eatab[(size_t)(r0 + r) * 512 + tid] = y;
    }
}

// ---------------------------------------------------------------------------
// Scan staging: one chunk of w/e/a gathered global->LDS via global_load_lds
// (no VGPR round-trip, each value fetched once per block).
// Layouts (linear in issue order):
//   wbuf[st*64 + m]      st in [0,CH_), m in [0,64)
//   ebuf[st*256 + col]   erase,  abuf same for add
// ---------------------------------------------------------------------------
__device__ __forceinline__ void stage_chunk(
    int tb, int tid,
    const int* __restrict__ qrow, const int* __restrict__ qarow,
    const float* __restrict__ wtab, const float* __restrict__ eatab,
    float* wbuf, float* ebuf, float* abuf)
{
    if (tid < 256) {
        int st = tb + (tid >> 4); if (st >= S_) st = S_ - 1;
        gload_lds16(&wtab[(size_t)qrow[st] * 64 + (tid & 15) * 4],
                    &wbuf[(tid & ~63) * 4]);
    }
    #pragma unroll
    for (int j = 0; j < 2; ++j) {
        const int idx = tid + 512 * j;          // 0..1023 quads
        int st = tb + (idx >> 6); if (st >= S_) st = S_ - 1;
        const int cq = (idx & 63) * 4;
        const float* rowp = &eatab[(size_t)qarow[st] * 512];
        gload_lds16(&rowp[cq],       &ebuf[(idx & ~63) * 4]);
        gload_lds16(&rowp[256 + cq], &abuf[(idx & ~63) * 4]);
    }
}

// ---------------------------------------------------------------------------
// Scan: 256 blocks (1/batch) x 512 threads (8 waves).
// Thread tid owns column pair col=(tid>>2)*2 and m-quarter mo=(tid&3)*16:
// mv0[4]/mv1[4] float4 state (32 VGPRs). Per step: 4 broadcast ds_read_b128
// (w) + 2 ds_read_b64 (e/a), 96 FMA, 2x2 quad shfl_xor, float2 store.
// All staging is async global->LDS, double-buffered per CH_-step chunk.
// ---------------------------------------------------------------------------
__global__ __launch_bounds__(512, 1) void scan_kernel(
    const int*   __restrict__ q_data,
    const int*   __restrict__ qa_data,
    const float* __restrict__ init_mv,
    const float* __restrict__ wtab,
    const float* __restrict__ eatab,
    float*       __restrict__ out)
{
    __shared__ float w_lds[2][CH_ * 64];     // 8 KB
    __shared__ float e_lds[2][CH_ * VD_];    // 32 KB
    __shared__ float a_lds[2][CH_ * VD_];    // 32 KB
    __shared__ int   qrow[S_];
    __shared__ int   qarow[S_];

    const int b   = blockIdx.x;
    const int tid = threadIdx.x;
    const int col = (tid >> 2) * 2;     // columns col, col+1
    const int ms  = tid & 3;
    const int mo  = ms * 16;

    for (int i = tid; i < S_; i += 512) {
        qrow[i]  = q_data[b * S_ + i];
        qarow[i] = qa_data[b * S_ + i];
    }
    __syncthreads();                     // qrow/qarow ready for staging

    stage_chunk(0, tid, qrow, qarow, wtab, eatab,
                w_lds[0], e_lds[0], a_lds[0]);

    // Mv state: m = mo + q*4 + k; column col in mv0, col+1 in mv1
    float4 mv0[4], mv1[4];
    #pragma unroll
    for (int q = 0; q < 4; ++q) {
        float2 i0 = *reinterpret_cast<const float2*>(&init_mv[(mo + q * 4 + 0) * VD_ + col]);
        float2 i1 = *reinterpret_cast<const float2*>(&init_mv[(mo + q * 4 + 1) * VD_ + col]);
        float2 i2 = *reinterpret_cast<const float2*>(&init_mv[(mo + q * 4 + 2) * VD_ + col]);
        float2 i3 = *reinterpret_cast<const float2*>(&init_mv[(mo + q * 4 + 3) * VD_ + col]);
        mv0[q].x = i0.x; mv1[q].x = i0.y;
        mv0[q].y = i1.x; mv1[q].y = i1.y;
        mv0[q].z = i2.x; mv1[q].z = i2.y;
        mv0[q].w = i3.x; mv1[q].w = i3.y;
    }
    if (ms == 0)
        *reinterpret_cast<float2*>(&out[(size_t)b * S_ * VD_ + col]) = make_float2(0.f, 0.f);

    __syncthreads();                     // chunk 0 staged (vmcnt drained)

    const int nch = (S_ + CH_ - 1) / CH_;
    for (int c = 0; c < nch; ++c) {
        const int  tb   = c * CH_;
        const int  full = (S_ - tb >= CH_);
        const int  buf  = c & 1;
        const bool hn   = (c + 1 < nch);

        // issue next chunk's async loads first; they land by the barrier
        if (hn)
            stage_chunk(tb + CH_, tid, qrow, qarow, wtab, eatab,
                        w_lds[buf ^ 1], e_lds[buf ^ 1], a_lds[buf ^ 1]);

        float* outp = &out[((size_t)b * S_ + tb + 1) * VD_ + col];

        #define STEP_BODY(tt)                                                       \
        {                                                                           \
            const int  t  = tb + (tt);                                              \
            const bool wr = qrow[t] >= 1;                                           \
            float2 ev = *reinterpret_cast<const float2*>(&e_lds[buf][(tt) * VD_ + col]); \
            float2 av = *reinterpret_cast<const float2*>(&a_lds[buf][(tt) * VD_ + col]); \
            const float em0 = wr ? ev.x : 0.f;                                      \
            const float am0 = wr ? av.x : 0.f;                                      \
            const float em1 = wr ? ev.y : 0.f;                                      \
            const float am1 = wr ? av.y : 0.f;                                      \
            const float* wrow = &w_lds[buf][(tt) * 64 + mo];                        \
            float r0a = 0.f, r0b = 0.f, r1a = 0.f, r1b = 0.f;                       \
            _Pragma("unroll")                                                       \
            for (int q = 0; q < 4; ++q) {                                           \
                float4 wq = *reinterpret_cast<const float4*>(wrow + q * 4);         \
                float4 v0 = mv0[q];                                                 \
                float4 v1 = mv1[q];                                                 \
                r0a = fmaf(wq.x, v0.x, r0a); r0b = fmaf(wq.y, v0.y, r0b);           \
                r0a = fmaf(wq.z, v0.z, r0a); r0b = fmaf(wq.w, v0.w, r0b);           \
                r1a = fmaf(wq.x, v1.x, r1a); r1b = fmaf(wq.y, v1.y, r1b);           \
                r1a = fmaf(wq.z, v1.z, r1a); r1b = fmaf(wq.w, v1.w, r1b);           \
                mv0[q].x = fmaf(wq.x, fmaf(-em0, v0.x, am0), v0.x);                 \
                mv0[q].y = fmaf(wq.y, fmaf(-em0, v0.y, am0), v0.y);                 \
                mv0[q].z = fmaf(wq.z, fmaf(-em0, v0.z, am0), v0.z);                 \
                mv0[q].w = fmaf(wq.w, fmaf(-em0, v0.w, am0), v0.w);                 \
                mv1[q].x = fmaf(wq.x, fmaf(-em1, v1.x, am1), v1.x);                 \
                mv1[q].y = fmaf(wq.y, fmaf(-em1, v1.y, am1), v1.y);                 \
                mv1[q].z = fmaf(wq.z, fmaf(-em1, v1.z, am1), v1.z);                 \
                mv1[q].w = fmaf(wq.w, fmaf(-em1, v1.w, am1), v1.w);                 \
            }                                                                       \
            float rd0 = r0a + r0b;                                                  \
            rd0 += __shfl_xor(rd0, 1);                                              \
            rd0 += __shfl_xor(rd0, 2);                                              \
            float rd1 = r1a + r1b;                                                  \
            rd1 += __shfl_xor(rd1, 1);                                              \
            rd1 += __shfl_xor(rd1, 2);                                              \
            if (ms == 0 && (t + 1 < S_))                                            \
                *reinterpret_cast<float2*>(&outp[(size_t)(tt) * VD_]) =             \
                    make_float2(rd0, rd1);                                          \
        }

        if (full) {
            #pragma unroll
            for (int tt = 0; tt < CH_; ++tt) STEP_BODY(tt)
        } else {
            #pragma unroll
            for (int tt = 0; tt < CH_; ++tt) {
                if (tb + tt < S_) STEP_BODY(tt)
            }
        }
        #undef STEP_BODY

        __syncthreads();   // next chunk staged + everyone done with buf
    }
}

// ---------------------------------------------------------------------------
extern "C" void kernel_launch(void* const* d_in, const int* in_sizes, int n_in,
                              void* d_out, int out_size, void* d_ws, size_t ws_size,
                              hipStream_t stream)
{
    const int*   q_data  = (const int*)  d_in[0];
    const int*   qa_data = (const int*)  d_in[1];
    const float* q_emb   = (const float*)d_in[2];
    const float* qa_emb  = (const float*)d_in[3];
    const float* key_mem = (const float*)d_in[4];
    const float* init_mv = (const float*)d_in[5];
    const float* erase_W = (const float*)d_in[6];
    const float* erase_b = (const float*)d_in[7];
    const float* add_W   = (const float*)d_in[8];
    const float* add_b   = (const float*)d_in[9];
    float* out = (float*)d_out;

    char* ws = (char*)d_ws;
    float4* kTq = (float4*)ws;
    size_t off = (size_t)2048 * sizeof(float4);               // 32 KB
    float* wtab = (float*)(ws + off);
    off += (size_t)WROWS * 64 * sizeof(float);                // 2.56 MB
    off = (off + 255) & ~(size_t)255;
    float* eatab = (float*)(ws + off);
    off += (size_t)EAROWS * 512 * sizeof(float);              // 40.96 MB

    kT_kernel<<<dim3(8), dim3(256), 0, stream>>>(key_mem, kTq);
    wtab_kernel<<<dim3((WROWS + 15) / 16), dim3(256), 0, stream>>>(
        q_emb, kTq, wtab);
    eatab_kernel<<<dim3((EAROWS + 15) / 16), dim3(512), 0, stream>>>(
        qa_emb, erase_W, erase_b, add_W, add_b, eatab);
    scan_kernel<<<dim3(B_), dim3(512), 0, stream>>>(
        q_data, qa_data, init_mv, wtab, eatab, out);
}

// Round 8
// 313.154 us; speedup vs baseline: 1.2394x; 1.0632x over previous
//
#include <hip/hip_runtime.h>
#include <math.h>

#define B_     256
#define S_     500
#define QD_    128
#define M_     64
#define VD_    256
#define CH_    16
#define NQ_    10000          // q indices in [0, 10000]
#define NQA_   20000          // qa indices in [0, 20000]
#define WROWS  (NQ_ + 1)
#define EAROWS (NQA_ + 1)

typedef unsigned int u32;

// global -> LDS async copy, 16B per lane. LDS dest must be wave-uniform
// base + lane*16 (we pass (idx & ~63)-based base, lanes fill linearly).
__device__ __forceinline__ void gload_lds16(const float* g, float* l)
{
    __builtin_amdgcn_global_load_lds(
        (const __attribute__((address_space(1))) u32*)(const void*)g,
        (__attribute__((address_space(3))) u32*)(void*)l, 16, 0, 0);
}

// quad-local reduction adds via DPP (pure VALU, no LDS pipe, no lgkmcnt):
// qadd1: x += x[lane^1]; qadd2: x += x[lane^2]
__device__ __forceinline__ float qadd1(float x)
{
    int r = __builtin_amdgcn_mov_dpp(__float_as_int(x), 0xB1, 0xF, 0xF, true);
    return x + __int_as_float(r);
}
__device__ __forceinline__ float qadd2(float x)
{
    int r = __builtin_amdgcn_mov_dpp(__float_as_int(x), 0x4E, 0xF, 0xF, true);
    return x + __int_as_float(r);
}

// ---------------------------------------------------------------------------
// Transpose key_mem [64][128] into quad layout kTq[k4*64 + m].
// ---------------------------------------------------------------------------
__global__ void kT_kernel(const float* __restrict__ key_mem, float4* __restrict__ kTq)
{
    int i = blockIdx.x * 256 + threadIdx.x;
    if (i < 32 * 64) {
        int m  = i & 63;
        int k4 = i >> 6;
        kTq[i] = *reinterpret_cast<const float4*>(&key_mem[m * QD_ + k4 * 4]);
    }
}

// ---------------------------------------------------------------------------
// wtab[r][m] = softmax_m( q_embed_w[r] . key_mem[m] ),  r in [0, WROWS)
// ---------------------------------------------------------------------------
__global__ __launch_bounds__(256) void wtab_kernel(
    const float*  __restrict__ q_embed_w,
    const float4* __restrict__ kTq,
    float*        __restrict__ wtab)
{
    __shared__ float4 q4[16][32];

    const int tid = threadIdx.x;
    const int r0  = blockIdx.x * 16;

    for (int i = tid; i < 512; i += 256) {
        int row = i >> 5, k4 = i & 31;
        int r   = r0 + row; if (r > NQ_) r = NQ_;
        q4[row][k4] = *reinterpret_cast<const float4*>(
            &q_embed_w[(size_t)r * QD_ + k4 * 4]);
    }
    __syncthreads();

    const int wave = tid >> 6, lane = tid & 63;
    const int rr = wave * 4;

    float s0 = 0.f, s1 = 0.f, s2 = 0.f, s3 = 0.f;
    for (int k4 = 0; k4 < 32; ++k4) {
        float4 kv = kTq[k4 * 64 + lane];
        float4 a0 = q4[rr + 0][k4];
        float4 a1 = q4[rr + 1][k4];
        float4 a2 = q4[rr + 2][k4];
        float4 a3 = q4[rr + 3][k4];
        s0 = fmaf(a0.x, kv.x, s0); s0 = fmaf(a0.y, kv.y, s0);
        s0 = fmaf(a0.z, kv.z, s0); s0 = fmaf(a0.w, kv.w, s0);
        s1 = fmaf(a1.x, kv.x, s1); s1 = fmaf(a1.y, kv.y, s1);
        s1 = fmaf(a1.z, kv.z, s1); s1 = fmaf(a1.w, kv.w, s1);
        s2 = fmaf(a2.x, kv.x, s2); s2 = fmaf(a2.y, kv.y, s2);
        s2 = fmaf(a2.z, kv.z, s2); s2 = fmaf(a2.w, kv.w, s2);
        s3 = fmaf(a3.x, kv.x, s3); s3 = fmaf(a3.y, kv.y, s3);
        s3 = fmaf(a3.z, kv.z, s3); s3 = fmaf(a3.w, kv.w, s3);
    }

    float s[4] = { s0, s1, s2, s3 };
    #pragma unroll
    for (int j = 0; j < 4; ++j) {
        float mx = s[j];
        #pragma unroll
        for (int off = 32; off; off >>= 1) mx = fmaxf(mx, __shfl_xor(mx, off));
        float e = __expf(s[j] - mx);
        float sum = e;
        #pragma unroll
        for (int off = 32; off; off >>= 1) sum += __shfl_xor(sum, off);
        if (r0 + rr + j < WROWS)
            wtab[(size_t)(r0 + rr + j) * 64 + lane] = e / sum;
    }
}

// ---------------------------------------------------------------------------
// eatab[r][0..255]   = sigmoid(qa_embed_w[r] @ erase_W + erase_b)
// eatab[r][256..511] = tanh   (qa_embed_w[r] @ add_W   + add_b)
// ---------------------------------------------------------------------------
__global__ __launch_bounds__(512) void eatab_kernel(
    const float* __restrict__ qa_embed_w,
    const float* __restrict__ erase_W,
    const float* __restrict__ erase_b,
    const float* __restrict__ add_W,
    const float* __restrict__ add_b,
    float*       __restrict__ eatab)
{
    __shared__ float4 qa4[16][32];

    const int tid = threadIdx.x;
    const int r0  = blockIdx.x * 16;

    {
        int row = tid >> 5, k4 = tid & 31;
        int r   = r0 + row; if (r > NQA_) r = NQA_;
        qa4[row][k4] = *reinterpret_cast<const float4*>(
            &qa_embed_w[(size_t)r * QD_ + k4 * 4]);
    }
    __syncthreads();

    const int  c   = tid & 255;
    const bool isE = tid < 256;
    const float* Wp = isE ? erase_W : add_W;

    float acc[16];
    #pragma unroll
    for (int r = 0; r < 16; ++r) acc[r] = 0.f;

    for (int k4 = 0; k4 < 32; ++k4) {
        float w0 = Wp[(size_t)(k4 * 4 + 0) * 256 + c];
        float w1 = Wp[(size_t)(k4 * 4 + 1) * 256 + c];
        float w2 = Wp[(size_t)(k4 * 4 + 2) * 256 + c];
        float w3 = Wp[(size_t)(k4 * 4 + 3) * 256 + c];
        #pragma unroll
        for (int r = 0; r < 16; ++r) {
            float4 qv = qa4[r][k4];
            acc[r] = fmaf(qv.x, w0, acc[r]);
            acc[r] = fmaf(qv.y, w1, acc[r]);
            acc[r] = fmaf(qv.z, w2, acc[r]);
            acc[r] = fmaf(qv.w, w3, acc[r]);
        }
    }

    const float bias = isE ? erase_b[c] : add_b[c];
    #pragma unroll
    for (int r = 0; r < 16; ++r) {
        float x = acc[r] + bias;
        float y;
        if (isE) {
            y = 1.f / (1.f + __expf(-x));
        } else {
            float t  = __expf(-2.f * fabsf(x));
            float ta = (1.f - t) / (1.f + t);
            y = (x < 0.f) ? -ta : ta;
        }
        if (r0 + r < EAROWS)
            eatab[(size_t)(r0 + r) * 512 + tid] = y;
    }
}

// ---------------------------------------------------------------------------
// Scan staging: one chunk of w/e/a gathered global->LDS via global_load_lds.
//   wbuf[st*64 + m], ebuf/abuf[st*256 + col]
// ---------------------------------------------------------------------------
__device__ __forceinline__ void stage_chunk(
    int tb, int tid,
    const int* __restrict__ qrow, const int* __restrict__ qarow,
    const float* __restrict__ wtab, const float* __restrict__ eatab,
    float* wbuf, float* ebuf, float* abuf)
{
    if (tid < 256) {
        int st = tb + (tid >> 4); if (st >= S_) st = S_ - 1;
        gload_lds16(&wtab[(size_t)qrow[st] * 64 + (tid & 15) * 4],
                    &wbuf[(tid & ~63) * 4]);
    }
    #pragma unroll
    for (int j = 0; j < 2; ++j) {
        const int idx = tid + 512 * j;          // 0..1023 quads
        int st = tb + (idx >> 6); if (st >= S_) st = S_ - 1;
        const int cq = (idx & 63) * 4;
        const float* rowp = &eatab[(size_t)qarow[st] * 512];
        gload_lds16(&rowp[cq],       &ebuf[(idx & ~63) * 4]);
        gload_lds16(&rowp[256 + cq], &abuf[(idx & ~63) * 4]);
    }
}

// ---------------------------------------------------------------------------
// Scan: 256 blocks (1/batch) x 512 threads (8 waves).
// Thread tid owns column pair col=(tid>>2)*2 and m-quarter mo=(tid&3)*16.
// Chunk compute is FULLY UNROLLED and software-pipelined with two named
// register sets (A/B): step tt issues step tt+1's w/e/a/qrow LDS loads
// before computing tt, so ds_read latency hides under 96 FMAs.
// Quad reduction via DPP adds (no ds_bpermute, no lgkmcnt in the tail).
// ---------------------------------------------------------------------------
__global__ __launch_bounds__(512, 1) void scan_kernel(
    const int*   __restrict__ q_data,
    const int*   __restrict__ qa_data,
    const float* __restrict__ init_mv,
    const float* __restrict__ wtab,
    const float* __restrict__ eatab,
    float*       __restrict__ out)
{
    __shared__ float w_lds[2][CH_ * 64];     // 8 KB
    __shared__ float e_lds[2][CH_ * VD_];    // 32 KB
    __shared__ float a_lds[2][CH_ * VD_];    // 32 KB
    __shared__ int   qrow[S_];
    __shared__ int   qarow[S_];

    const int b   = blockIdx.x;
    const int tid = threadIdx.x;
    const int col = (tid >> 2) * 2;     // columns col, col+1
    const int ms  = tid & 3;
    const int mo  = ms * 16;

    for (int i = tid; i < S_; i += 512) {
        qrow[i]  = q_data[b * S_ + i];
        qarow[i] = qa_data[b * S_ + i];
    }
    __syncthreads();                     // qrow/qarow ready for staging

    stage_chunk(0, tid, qrow, qarow, wtab, eatab,
                w_lds[0], e_lds[0], a_lds[0]);

    // Mv state: m = mo + q*4 + k; column col in mv0, col+1 in mv1
    float4 mv0[4], mv1[4];
    #pragma unroll
    for (int q = 0; q < 4; ++q) {
        float2 i0 = *reinterpret_cast<const float2*>(&init_mv[(mo + q * 4 + 0) * VD_ + col]);
        float2 i1 = *reinterpret_cast<const float2*>(&init_mv[(mo + q * 4 + 1) * VD_ + col]);
        float2 i2 = *reinterpret_cast<const float2*>(&init_mv[(mo + q * 4 + 2) * VD_ + col]);
        float2 i3 = *reinterpret_cast<const float2*>(&init_mv[(mo + q * 4 + 3) * VD_ + col]);
        mv0[q].x = i0.x; mv1[q].x = i0.y;
        mv0[q].y = i1.x; mv1[q].y = i1.y;
        mv0[q].z = i2.x; mv1[q].z = i2.y;
        mv0[q].w = i3.x; mv1[q].w = i3.y;
    }
    if (ms == 0)
        *reinterpret_cast<float2*>(&out[(size_t)b * S_ * VD_ + col]) = make_float2(0.f, 0.f);

    __syncthreads();                     // chunk 0 staged (vmcnt drained)

    const int nch = (S_ + CH_ - 1) / CH_;
    for (int c = 0; c < nch; ++c) {
        const int  tb   = c * CH_;
        const int  full = (S_ - tb >= CH_);
        const int  buf  = c & 1;
        const bool hn   = (c + 1 < nch);

        // issue next chunk's async loads first; they land by the barrier
        if (hn)
            stage_chunk(tb + CH_, tid, qrow, qarow, wtab, eatab,
                        w_lds[buf ^ 1], e_lds[buf ^ 1], a_lds[buf ^ 1]);

        const float* wb = &w_lds[buf][mo];
        const float* eb = &e_lds[buf][col];
        const float* ab = &a_lds[buf][col];
        float* outp = &out[((size_t)b * S_ + tb + 1) * VD_ + col];

        float4 w0A, w1A, w2A, w3A, w0B, w1B, w2B, w3B;
        float2 evA, avA, evB, avB;
        int    qrA, qrB;

        #define LOADS(tt, SS)                                                   \
            w0##SS = *reinterpret_cast<const float4*>(wb + (tt) * 64 + 0);      \
            w1##SS = *reinterpret_cast<const float4*>(wb + (tt) * 64 + 4);      \
            w2##SS = *reinterpret_cast<const float4*>(wb + (tt) * 64 + 8);      \
            w3##SS = *reinterpret_cast<const float4*>(wb + (tt) * 64 + 12);     \
            ev##SS = *reinterpret_cast<const float2*>(eb + (tt) * VD_);         \
            av##SS = *reinterpret_cast<const float2*>(ab + (tt) * VD_);         \
            qr##SS = qrow[tb + (tt)];

        #define QCORE(WQ, q) {                                                  \
            float4 v0 = mv0[q]; float4 v1 = mv1[q];                             \
            r0a = fmaf(WQ.x, v0.x, r0a); r0b = fmaf(WQ.y, v0.y, r0b);           \
            r0a = fmaf(WQ.z, v0.z, r0a); r0b = fmaf(WQ.w, v0.w, r0b);           \
            r1a = fmaf(WQ.x, v1.x, r1a); r1b = fmaf(WQ.y, v1.y, r1b);           \
            r1a = fmaf(WQ.z, v1.z, r1a); r1b = fmaf(WQ.w, v1.w, r1b);           \
            mv0[q].x = fmaf(WQ.x, fmaf(-em0, v0.x, am0), v0.x);                 \
            mv0[q].y = fmaf(WQ.y, fmaf(-em0, v0.y, am0), v0.y);                 \
            mv0[q].z = fmaf(WQ.z, fmaf(-em0, v0.z, am0), v0.z);                 \
            mv0[q].w = fmaf(WQ.w, fmaf(-em0, v0.w, am0), v0.w);                 \
            mv1[q].x = fmaf(WQ.x, fmaf(-em1, v1.x, am1), v1.x);                 \
            mv1[q].y = fmaf(WQ.y, fmaf(-em1, v1.y, am1), v1.y);                 \
            mv1[q].z = fmaf(WQ.z, fmaf(-em1, v1.z, am1), v1.z);                 \
            mv1[q].w = fmaf(WQ.w, fmaf(-em1, v1.w, am1), v1.w);                 \
        }

        #define COMP(tt, SS, GUARD) {                                           \
            const bool wr  = qr##SS >= 1;                                       \
            const float em0 = wr ? ev##SS.x : 0.f;                              \
            const float am0 = wr ? av##SS.x : 0.f;                              \
            const float em1 = wr ? ev##SS.y : 0.f;                              \
            const float am1 = wr ? av##SS.y : 0.f;                              \
            float r0a = 0.f, r0b = 0.f, r1a = 0.f, r1b = 0.f;                   \
            QCORE(w0##SS, 0) QCORE(w1##SS, 1) QCORE(w2##SS, 2) QCORE(w3##SS, 3) \
            float rd0 = qadd2(qadd1(r0a + r0b));                                \
            float rd1 = qadd2(qadd1(r1a + r1b));                                \
            if (ms == 0 && (GUARD))                                             \
                *reinterpret_cast<float2*>(&outp[(size_t)(tt) * VD_]) =         \
                    make_float2(rd0, rd1);                                      \
        }

        if (full) {
            LOADS(0, A)
            LOADS(1,  B) COMP(0,  A, true)
            LOADS(2,  A) COMP(1,  B, true)
            LOADS(3,  B) COMP(2,  A, true)
            LOADS(4,  A) COMP(3,  B, true)
            LOADS(5,  B) COMP(4,  A, true)
            LOADS(6,  A) COMP(5,  B, true)
            LOADS(7,  B) COMP(6,  A, true)
            LOADS(8,  A) COMP(7,  B, true)
            LOADS(9,  B) COMP(8,  A, true)
            LOADS(10, A) COMP(9,  B, true)
            LOADS(11, B) COMP(10, A, true)
            LOADS(12, A) COMP(11, B, true)
            LOADS(13, B) COMP(12, A, true)
            LOADS(14, A) COMP(13, B, true)
            LOADS(15, B) COMP(14, A, true)
            COMP(15, B, true)
        } else {
            #define TSTEP(tt)                                                   \
            if (tb + (tt) < S_) {                                               \
                LOADS(tt, A)                                                    \
                COMP(tt, A, tb + (tt) + 1 < S_)                                 \
            }
            TSTEP(0)  TSTEP(1)  TSTEP(2)  TSTEP(3)
            TSTEP(4)  TSTEP(5)  TSTEP(6)  TSTEP(7)
            TSTEP(8)  TSTEP(9)  TSTEP(10) TSTEP(11)
            TSTEP(12) TSTEP(13) TSTEP(14) TSTEP(15)
            #undef TSTEP
        }

        #undef COMP
        #undef QCORE
        #undef LOADS

        __syncthreads();   // next chunk staged + everyone done with buf
    }
}

// ---------------------------------------------------------------------------
extern "C" void kernel_launch(void* const* d_in, const int* in_sizes, int n_in,
                              void* d_out, int out_size, void* d_ws, size_t ws_size,
                              hipStream_t stream)
{
    const int*   q_data  = (const int*)  d_in[0];
    const int*   qa_data = (const int*)  d_in[1];
    const float* q_emb   = (const float*)d_in[2];
    const float* qa_emb  = (const float*)d_in[3];
    const float* key_mem = (const float*)d_in[4];
    const float* init_mv = (const float*)d_in[5];
    const float* erase_W = (const float*)d_in[6];
    const float* erase_b = (const float*)d_in[7];
    const float* add_W   = (const float*)d_in[8];
    const float* add_b   = (const float*)d_in[9];
    float* out = (float*)d_out;

    char* ws = (char*)d_ws;
    float4* kTq = (float4*)ws;
    size_t off = (size_t)2048 * sizeof(float4);               // 32 KB
    float* wtab = (float*)(ws + off);
    off += (size_t)WROWS * 64 * sizeof(float);                // 2.56 MB
    off = (off + 255) & ~(size_t)255;
    float* eatab = (float*)(ws + off);
    off += (size_t)EAROWS * 512 * sizeof(float);              // 40.96 MB

    kT_kernel<<<dim3(8), dim3(256), 0, stream>>>(key_mem, kTq);
    wtab_kernel<<<dim3((WROWS + 15) / 16), dim3(256), 0, stream>>>(
        q_emb, kTq, wtab);
    eatab_kernel<<<dim3((EAROWS + 15) / 16), dim3(512), 0, stream>>>(
        qa_emb, erase_W, erase_b, add_W, add_b, eatab);
    scan_kernel<<<dim3(B_), dim3(512), 0, stream>>>(
        q_data, qa_data, init_mv, wtab, eatab, out);
}